// Round 5
// baseline (122.139 us; speedup 1.0000x reference)
//
#include <hip/hip_runtime.h>

typedef __attribute__((__ext_vector_type__(8))) _Float16 f16x8;
typedef __attribute__((__ext_vector_type__(4))) float f32x4;
typedef __attribute__((__ext_vector_type__(4))) int i32x4;

#define HW 56
#define HW2 3136
#define CIN 128
#define COUT 256
#define NB 32
#define NPIX 100352  // 32*3136
#define PH 58        // padded spatial dim (1-px halo)

static __device__ __forceinline__ unsigned short f2h(float f) {
  _Float16 h = (_Float16)f;
  return __builtin_bit_cast(unsigned short, h);
}

#define GLD_LDS16(g, l)                                          \
  __builtin_amdgcn_global_load_lds(                              \
      (const __attribute__((address_space(1))) void*)(g),        \
      (__attribute__((address_space(3))) void*)(l), 16, 0, 0)

// ---- zero the 1-pixel halo of x_pad ----
__global__ __launch_bounds__(256) void zero_halo(unsigned short* __restrict__ xp) {
  int t = blockIdx.x * 256 + threadIdx.x;  // 32*228*16 threads
  int ck = t & 15;                          // 16B chunk in 256B pixel
  int pi = t >> 4;
  int b = pi / 228, r = pi - b * 228;
  int h, w;
  if (r < 58) { h = 0; w = r; }
  else if (r < 116) { h = 57; w = r - 58; }
  else { int q = r - 116; h = 1 + (q >> 1); w = (q & 1) * 57; }
  size_t off = (((size_t)(b * PH + h) * PH + w) << 8) + (ck << 4);
  *reinterpret_cast<i32x4*>((char*)xp + off) = (i32x4){0, 0, 0, 0};
}

// ---- prep_x: x NCHW f32 -> x_pad [32][58][58][128] f16 (interior), plus channel-sum xs ----
__global__ __launch_bounds__(256) void prep_x(const float* __restrict__ x,
                                              unsigned short* __restrict__ xp,
                                              float* __restrict__ xs) {
  __shared__ float tile[CIN * 57];  // [c][w], stride 57 kills bank conflicts
  const int bh = blockIdx.x;        // b*56 + h
  const float* src = x + (size_t)(bh / HW) * CIN * HW2 + (size_t)(bh % HW) * HW;
  for (int idx = threadIdx.x; idx < CIN * HW; idx += 256) {
    int c = idx / HW, w = idx - c * HW;
    tile[c * 57 + w] = src[(size_t)c * HW2 + w];
  }
  __syncthreads();
  unsigned short* dst =
      xp + (((size_t)(bh / HW) * PH + (bh % HW) + 1) * PH + 1) * CIN;
  for (int idx = threadIdx.x; idx < HW * (CIN / 2); idx += 256) {
    int w = idx >> 6;         // pixel within row
    int c = (idx & 63) << 1;  // channel pair
    unsigned lo = f2h(tile[c * 57 + w]);
    unsigned hi = f2h(tile[(c + 1) * 57 + w]);
    *reinterpret_cast<unsigned*>(&dst[w * CIN + c]) = lo | (hi << 16);
  }
  if (threadIdx.x < HW) {
    float s = 0.f;
    for (int c = 0; c < CIN; ++c) s += tile[c * 57 + threadIdx.x];
    xs[(size_t)bh * HW + threadIdx.x] = s;
  }
}

// ---- prep_w: core [COUT][CIN][3][3] f32 -> w_t [COUT][9][CIN] f16 ----
__global__ __launch_bounds__(256) void prep_w(const float* __restrict__ core,
                                              unsigned short* __restrict__ w_t) {
  int i = blockIdx.x * 256 + threadIdx.x;  // < 256*9*128
  int c = i & 127;
  int p = (i >> 7) % 9;
  int m = i / (9 * 128);
  w_t[i] = f2h(core[(size_t)(m * CIN + c) * 9 + p]);
}

// ---- periphery stencil on xs ----
__global__ __launch_bounds__(256) void periph_k(const float* __restrict__ xs,
                                                const float* __restrict__ per,
                                                float* __restrict__ po) {
  int n = blockIdx.x * 256 + threadIdx.x;
  int b = n / HW2, r = n - b * HW2;
  int ho = r / HW, wo = r - ho * HW;
  const float* xb = xs + (size_t)b * HW2;
  const int pdy[16] = {0,0,0,0,0,1,1,2,2,3,3,4,4,4,4,4};
  const int pdx[16] = {0,1,2,3,4,0,4,0,4,0,4,0,1,2,3,4};
  float acc = 0.f;
#pragma unroll
  for (int t = 0; t < 16; ++t) {
    int h = ho + pdy[t] - 2, w = wo + pdx[t] - 2;
    if ((unsigned)h < HW && (unsigned)w < HW) acc += per[t] * xb[h * HW + w];
  }
  po[n] = acc;
}

// ---- implicit-GEMM conv, 8-phase-per-2-K-tiles schedule (T2+T3+T4+T5) ----
// BM=256 BN=256 BK=64, 8 waves (2M x 4N), wave tile 128x64. 18 K-tiles,
// buffer t&1 (2 x 64KB). 4 phases per K-tile, 16 MFMA each. Prefetch depth
// = 2 K-tiles: during group t, stage tile t+2 into buffer t&1 exactly where
// dead: B(t) fully read at phase 0 -> stage B(t+2) at phases 1,2; A(t) fully
// read after phase 3's ds_reads -> stage A(t+2) after phase 3's lgkmcnt(0) +
// mid-barrier. One counted vmcnt per group (end of phase 3): vmcnt(8) =
// stages issued during this group; retirement is issue-ordered, so <=8
// outstanding implies tile t+1 (older) fully landed.
__global__ __launch_bounds__(512, 2) void gemm_k(const unsigned short* __restrict__ xp,
                                                 const unsigned short* __restrict__ w_t,
                                                 const float* __restrict__ po,
                                                 const float* __restrict__ thresh,
                                                 const float* __restrict__ scale,
                                                 float* __restrict__ out) {
  __shared__ __align__(16) char sMem[2 * 65536 + 1024];

  const int tid = threadIdx.x;
  const int lane = tid & 63;
  const int wid = tid >> 6;  // 0..7
  const int wm = wid >> 2;   // 0..1 (cout half)
  const int wn = wid & 3;    // 0..3 (pixel quarter)

  // XCD-chunked bijective swizzle: nwg=392=8*49
  const int bid = blockIdx.x;
  const int n0 = ((bid & 7) * 49 + (bid >> 3)) << 8;

  float* sTh = (float*)(sMem + 131072);
  if (tid < 256) sTh[tid] = thresh[tid];

  // ---- staging addresses (linear LDS dest + inverse-swizzled global src) ----
  const int slot = tid & 7;
  const int trow = tid >> 3;               // 0..63
  const int sw = (slot ^ (trow & 7)) << 4; // pre-swizzled 16B slot
  const char* xpc = (const char*)xp;
  const char* wtc = (const char*)w_t;
  int aOff[4], bOff[4];
#pragma unroll
  for (int q = 0; q < 4; ++q) {
    int row = q * 64 + trow;               // 0..255
    aOff[q] = row * (9 * 256) + sw;        // w_t row stride = 9*128ch*2B
    int n = n0 + row;
    int b = n / HW2, rr = n - b * HW2;
    int h = rr / HW, w = rr - h * HW;
    bOff[q] = ((b * PH + h + 1) * PH + (w + 1)) * 256 + sw;  // center tap
  }
  const int ldsw = wid * 1024;  // wave-uniform; lane*16 appended by HW

  auto stageA4 = [&](char* base, int offA) {
#pragma unroll
    for (int q = 0; q < 4; ++q)
      GLD_LDS16(wtc + aOff[q] + offA, base + q * 8192 + ldsw);
  };
  auto stageB2 = [&](char* base, int offB, int half) {
#pragma unroll
    for (int q = 0; q < 2; ++q) {
      int qq = half * 2 + q;
      GLD_LDS16(xpc + bOff[qq] + offB, base + 32768 + qq * 8192 + ldsw);
    }
  };
  auto tileOffA = [](int t) { return ((t >> 1) << 8) + ((t & 1) << 7); };
  auto tileOffB = [](int t) {
    int p = t >> 1;
    int dy = p / 3 - 1, dx = p - (p / 3) * 3 - 1;
    return ((dy * PH + dx) << 8) + ((t & 1) << 7);
  };

  // ---- fragment read offsets (swizzled) ----
  int aro[8][2], bro[4][2];
#pragma unroll
  for (int i = 0; i < 8; ++i)
#pragma unroll
    for (int ko = 0; ko < 2; ++ko) {
      int rowA = wm * 128 + i * 16 + (lane & 15);
      int boc = ko * 64 + ((lane >> 4) << 4);
      aro[i][ko] = rowA * 128 + (boc ^ ((rowA & 7) << 4));
    }
#pragma unroll
  for (int j = 0; j < 4; ++j)
#pragma unroll
    for (int ko = 0; ko < 2; ++ko) {
      int rowB = wn * 64 + j * 16 + (lane & 15);
      int boc = ko * 64 + ((lane >> 4) << 4);
      bro[j][ko] = 32768 + rowB * 128 + (boc ^ ((rowB & 7) << 4));
    }

  f32x4 acc[8][4] = {};

  // ---- prologue: stage tiles 0 (buf0) and 1 (buf1) ----
  stageB2(sMem, tileOffB(0), 0);
  stageB2(sMem, tileOffB(0), 1);
  stageA4(sMem, tileOffA(0));
  stageB2(sMem + 65536, tileOffB(1), 0);
  stageB2(sMem + 65536, tileOffB(1), 1);
  stageA4(sMem + 65536, tileOffA(1));
  asm volatile("s_waitcnt vmcnt(8)" ::: "memory");  // tile 0 landed
  __builtin_amdgcn_s_barrier();

  for (int t = 0; t < 18; ++t) {
    char* base = sMem + (t & 1) * 65536;
    const int tn = t + 2;
    const bool st = tn < 18;
    const int offAN = st ? tileOffA(tn) : 0;
    const int offBN = st ? tileOffB(tn) : 0;

    f16x8 bfr[4][2];
#pragma unroll
    for (int q = 0; q < 4; ++q) {
      // ---- ds-reads for this phase ----
      if (q == 0) {
#pragma unroll
        for (int j = 0; j < 4; ++j)
#pragma unroll
          for (int ko = 0; ko < 2; ++ko)
            bfr[j][ko] = *reinterpret_cast<const f16x8*>(base + bro[j][ko]);
      }
      f16x8 aA[2][2];
#pragma unroll
      for (int di = 0; di < 2; ++di)
#pragma unroll
        for (int ko = 0; ko < 2; ++ko)
          aA[di][ko] = *reinterpret_cast<const f16x8*>(base + aro[2 * q + di][ko]);

      // ---- stage (into regions of THIS buffer that are already dead) ----
      if (st && q == 1) stageB2(base, offBN, 0);
      if (st && q == 2) stageB2(base, offBN, 1);
      if (q == 3) asm volatile("s_waitcnt lgkmcnt(0)" ::: "memory");  // all A(t) reads retired

      __builtin_amdgcn_s_barrier();  // mid: phase's reads issued by all waves

      if (st && q == 3) stageA4(base, offAN);  // A(t) dead across all waves now

      // ---- 16 MFMA ----
      __builtin_amdgcn_s_setprio(1);
#pragma unroll
      for (int di = 0; di < 2; ++di)
#pragma unroll
        for (int j = 0; j < 4; ++j) {
          acc[2 * q + di][j] =
              __builtin_amdgcn_mfma_f32_16x16x32_f16(aA[di][0], bfr[j][0], acc[2 * q + di][j], 0, 0, 0);
          acc[2 * q + di][j] =
              __builtin_amdgcn_mfma_f32_16x16x32_f16(aA[di][1], bfr[j][1], acc[2 * q + di][j], 0, 0, 0);
        }
      __builtin_amdgcn_s_setprio(0);

      if (q == 3) {
        if (t <= 15) {
          asm volatile("s_waitcnt vmcnt(8)" ::: "memory");   // tile t+1 landed
        } else if (t == 16) {
          asm volatile("s_waitcnt vmcnt(0)" ::: "memory");   // tile 17 landed
        }
      }
      __builtin_amdgcn_s_barrier();  // trailing
    }
  }

  const float sc = scale[0];
#pragma unroll
  for (int j = 0; j < 4; ++j) {
    int n = n0 + wn * 64 + j * 16 + (lane & 15);
    int b = n / HW2;
    int r = n - b * HW2;  // ho*56+wo
    float pv = po[n];
    float* op = out + (size_t)b * (COUT * HW2) + r;
#pragma unroll
    for (int i = 0; i < 8; ++i) {
      int cl = wm * 128 + i * 16 + ((lane >> 4) << 2);
#pragma unroll
      for (int q = 0; q < 4; ++q) {
        float cv = acc[i][j][q];
        float g = 1.f / (1.f + __expf(-sc * (cv - sTh[cl + q])));
        op[(size_t)(cl + q) * HW2] = cv + g * pv;
      }
    }
  }
}

extern "C" void kernel_launch(void* const* d_in, const int* in_sizes, int n_in,
                              void* d_out, int out_size, void* d_ws, size_t ws_size,
                              hipStream_t stream) {
  (void)in_sizes; (void)n_in; (void)out_size; (void)ws_size;
  const float* x      = (const float*)d_in[0];
  const float* core   = (const float*)d_in[1];
  const float* per    = (const float*)d_in[2];
  const float* thresh = (const float*)d_in[3];
  const float* scale  = (const float*)d_in[4];
  float* out = (float*)d_out;

  char* ws = (char*)d_ws;
  unsigned short* xp  = (unsigned short*)ws;                  // 32*58*58*128*2 = 27,557,888 B
  unsigned short* w_t = (unsigned short*)(ws + 27557888);     // 589,824 B
  float* xs           = (float*)(ws + 28147712);              // 401,408 B
  float* po           = (float*)(ws + 28549120);              // 401,408 B

  zero_halo<<<(NB * 228 * 16) / 256, 256, 0, stream>>>(xp);
  prep_x<<<NB * HW, 256, 0, stream>>>(x, xp, xs);
  prep_w<<<(COUT * 9 * CIN) / 256, 256, 0, stream>>>(core, w_t);
  periph_k<<<NPIX / 256, 256, 0, stream>>>(xs, per, po);
  gemm_k<<<NPIX / 256, 512, 0, stream>>>(xp, w_t, po, thresh, scale, out);
}